// Round 7
// baseline (1069.280 us; speedup 1.0000x reference)
//
#include <hip/hip_runtime.h>
#include <cstddef>
#include <cstdint>

#define B_ 64
#define T_ 800
#define D_ 80
#define H_ 128
#define K_ 39

typedef _Float16 h2_t __attribute__((ext_vector_type(2)));

__device__ __forceinline__ float fdot2_(h2_t a, h2_t b, float c) {
#if __has_builtin(__builtin_amdgcn_fdot2)
  return __builtin_amdgcn_fdot2(a, b, c, false);
#else
  return c + (float)a.x * (float)b.x + (float)a.y * (float)b.y;
#endif
}

__device__ __forceinline__ h2_t asH2u_(uint32_t u) { return __builtin_bit_cast(h2_t, u); }
__device__ __forceinline__ h2_t asH2f_(float f)    { return __builtin_bit_cast(h2_t, f); }

__device__ __forceinline__ float sigf_(float x)  { return 1.0f / (1.0f + __expf(-x)); }
__device__ __forceinline__ float tanhf_(float x) { return 2.0f / (1.0f + __expf(-2.0f * x)) - 1.0f; }

__device__ __forceinline__ float laneb_(float v, int lane) {
  return __builtin_bit_cast(float, __builtin_amdgcn_readlane(__builtin_bit_cast(int, v), lane));
}
__device__ __forceinline__ uint32_t lanebu_(uint32_t v, int lane) {
  return (uint32_t)__builtin_amdgcn_readlane((int)v, lane);
}

// LDS-only barrier: waits LDS ops but does NOT drain vmem, so global
// prefetch loads / h stores stay in flight across steps (HIP __syncthreads
// would emit s_waitcnt vmcnt(0) and serialize the prefetch pipeline).
__device__ __forceinline__ void barrier_lds_() {
  asm volatile("s_waitcnt lgkmcnt(0)" ::: "memory");
  __builtin_amdgcn_s_barrier();
}

// Shared lane->gate-rows mapping (lstm and xw's paired output layout).
// wave w, lane L: unit = w*32 + (L>>1); role = L&1.
// role0 owns (i,g) rows of unit; role1 owns (f,o). shfl_xor(1) pairs them.
__device__ __forceinline__ void rows_of_(int tid, int& unit, int& role, int& r0, int& r1) {
  const int w = tid >> 6, L = tid & 63;
  unit = w * 32 + (L >> 1);
  role = L & 1;
  r0 = role * H_ + unit;            // i (role0) or f (role1)
  r1 = 2 * H_ + role * H_ + unit;   // g (role0) or o (role1)
}

// ---------------------------------------------------------------------------
// xw: paired layout xwp[dir][bt][tid] (h2 = {dot(x, Wih[r0(tid)]), dot(.., r1)})
// Merged dirs: thread owns 4 W rows (2 per dir) register-resident (160 h2).
// 256-row bt tile staged in LDS as f16; broadcast b128 reads. Grid 200 = one
// WG per CU, single round.
// ---------------------------------------------------------------------------
__global__ __launch_bounds__(256, 1)
void xw_kernel(const float* __restrict__ x,
               const float* __restrict__ Wih_f, const float* __restrict__ Wih_b,
               h2_t* __restrict__ xwp)
{
  const int tid = threadIdx.x;
  int unit, role, r0, r1; rows_of_(tid, unit, role, r0, r1);

  h2_t wf0[40], wf1[40], wb0[40], wb1[40];
  #pragma unroll
  for (int i = 0; i < 40; ++i) {
    float2 a = *(const float2*)(Wih_f + (size_t)r0 * D_ + 2 * i);
    float2 b = *(const float2*)(Wih_f + (size_t)r1 * D_ + 2 * i);
    float2 c = *(const float2*)(Wih_b + (size_t)r0 * D_ + 2 * i);
    float2 d = *(const float2*)(Wih_b + (size_t)r1 * D_ + 2 * i);
    wf0[i].x = (_Float16)a.x; wf0[i].y = (_Float16)a.y;
    wf1[i].x = (_Float16)b.x; wf1[i].y = (_Float16)b.y;
    wb0[i].x = (_Float16)c.x; wb0[i].y = (_Float16)c.y;
    wb1[i].x = (_Float16)d.x; wb1[i].y = (_Float16)d.y;
  }

  __shared__ alignas(16) _Float16 xsh[256 * D_];   // 40 KB
  const int bt0 = blockIdx.x * 256;
  {
    const float4* src = (const float4*)(x + (size_t)bt0 * D_);
    for (int i = tid; i < 256 * D_ / 4; i += 256) {
      float4 v = src[i];
      h2_t p0, p1;
      p0.x = (_Float16)v.x; p0.y = (_Float16)v.y;
      p1.x = (_Float16)v.z; p1.y = (_Float16)v.w;
      uint2 pk;
      pk.x = __builtin_bit_cast(uint32_t, p0);
      pk.y = __builtin_bit_cast(uint32_t, p1);
      *(uint2*)&xsh[i * 4] = pk;
    }
  }
  __syncthreads();

  for (int row = 0; row < 256; ++row) {
    const float4* xr4 = (const float4*)(xsh + row * D_);
    float f0a = 0.f, f0b = 0.f, f1a = 0.f, f1b = 0.f;
    float g0a = 0.f, g0b = 0.f, g1a = 0.f, g1b = 0.f;
    #pragma unroll
    for (int ch = 0; ch < 10; ++ch) {
      float4 f = xr4[ch];
      h2_t q0 = asH2f_(f.x), q1 = asH2f_(f.y), q2 = asH2f_(f.z), q3 = asH2f_(f.w);
      f0a = fdot2_(wf0[4*ch],   q0, f0a); f0b = fdot2_(wf0[4*ch+1], q1, f0b);
      f0a = fdot2_(wf0[4*ch+2], q2, f0a); f0b = fdot2_(wf0[4*ch+3], q3, f0b);
      f1a = fdot2_(wf1[4*ch],   q0, f1a); f1b = fdot2_(wf1[4*ch+1], q1, f1b);
      f1a = fdot2_(wf1[4*ch+2], q2, f1a); f1b = fdot2_(wf1[4*ch+3], q3, f1b);
      g0a = fdot2_(wb0[4*ch],   q0, g0a); g0b = fdot2_(wb0[4*ch+1], q1, g0b);
      g0a = fdot2_(wb0[4*ch+2], q2, g0a); g0b = fdot2_(wb0[4*ch+3], q3, g0b);
      g1a = fdot2_(wb1[4*ch],   q0, g1a); g1b = fdot2_(wb1[4*ch+1], q1, g1b);
      g1a = fdot2_(wb1[4*ch+2], q2, g1a); g1b = fdot2_(wb1[4*ch+3], q3, g1b);
    }
    const size_t bt = (size_t)bt0 + row;
    h2_t of; of.x = (_Float16)(f0a + f0b); of.y = (_Float16)(f1a + f1b);
    h2_t ob; ob.x = (_Float16)(g0a + g0b); ob.y = (_Float16)(g1a + g1b);
    xwp[bt * 256 + tid] = of;
    xwp[(size_t)B_ * T_ * 256 + bt * 256 + tid] = ob;
  }
}

// ---------------------------------------------------------------------------
// Recurrent LSTM. Grid 128 (one WG per (b,dir)), 256 threads.
// h broadcast via readlane (lane L holds h2[L]; 1 ds_read_b32/wave/step),
// single LDS-only barrier per step, double-buffered h by parity.
// Whh rows f16x2 register-resident (128 VGPRs). xw prefetched 2 steps ahead;
// raw barrier keeps those loads in flight.
// ---------------------------------------------------------------------------
template<int USE_XW>
__global__ __launch_bounds__(256, 1)
void lstm_kernel(const float* __restrict__ x,
                 const float* __restrict__ Wih_f, const float* __restrict__ Whh_f,
                 const float* __restrict__ bih_f, const float* __restrict__ bhh_f,
                 const float* __restrict__ Wih_b, const float* __restrict__ Whh_b,
                 const float* __restrict__ bih_b, const float* __restrict__ bhh_b,
                 const h2_t* __restrict__ xwp,
                 _Float16* __restrict__ hcat)
{
  const int bb  = blockIdx.x & 63;
  const int dir = blockIdx.x >> 6;
  const float* Whh = dir ? Whh_b : Whh_f;
  const float* Wih = dir ? Wih_b : Wih_f;
  const float* bih = dir ? bih_b : bih_f;
  const float* bhh = dir ? bhh_b : bhh_f;

  const int tid  = threadIdx.x;
  const int lane = tid & 63;
  int unit, role, r0, r1; rows_of_(tid, unit, role, r0, r1);

  h2_t w0[64], w1[64];
  #pragma unroll
  for (int j = 0; j < 64; ++j) {
    float2 a = *(const float2*)(Whh + (size_t)r0 * H_ + 2 * j);
    float2 d = *(const float2*)(Whh + (size_t)r1 * H_ + 2 * j);
    w0[j].x = (_Float16)a.x; w0[j].y = (_Float16)a.y;
    w1[j].x = (_Float16)d.x; w1[j].y = (_Float16)d.y;
  }
  h2_t wx0[40], wx1[40];
  if (!USE_XW) {
    #pragma unroll
    for (int i = 0; i < 40; ++i) {
      float2 a = *(const float2*)(Wih + (size_t)r0 * D_ + 2 * i);
      float2 d = *(const float2*)(Wih + (size_t)r1 * D_ + 2 * i);
      wx0[i].x = (_Float16)a.x; wx0[i].y = (_Float16)a.y;
      wx1[i].x = (_Float16)d.x; wx1[i].y = (_Float16)d.y;
    }
  }
  const float bias0 = bih[r0] + bhh[r0];
  const float bias1 = bih[r1] + bhh[r1];

  __shared__ alignas(8) _Float16 hsf[2][H_];   // double-buffered h (f16)
  __shared__ uint32_t xs2[2][64];              // fallback x staging (h2)

  if (tid < H_) hsf[0][tid] = (_Float16)0.0f;
  if (!USE_XW && tid < 64) { xs2[0][tid] = 0u; xs2[1][tid] = 0u; }
  float c = 0.0f;   // role1 owns cell state of its unit

  const h2_t*  xwb = xwp + ((size_t)dir * B_ * T_ + (size_t)bb * T_) * 256;
  const float* xb  = x + (size_t)bb * T_ * D_;
  _Float16*    hb  = hcat + (size_t)bb * T_ * (2 * H_) + dir * H_;

  // prime the 2-deep prefetch pipeline
  h2_t xwA; xwA.x = (_Float16)0.f; xwA.y = (_Float16)0.f;
  h2_t xwB = xwA, xpend = xwA;
  {
    const int tq0 = dir ? (T_ - 1) : 0;
    const int tq1 = dir ? (T_ - 2) : 1;
    if (USE_XW) {
      xwA = xwb[(size_t)tq0 * 256 + tid];
      xwB = xwb[(size_t)tq1 * 256 + tid];
    } else if (tid < 40) {
      float2 v0 = *(const float2*)(xb + (size_t)tq0 * D_ + 2 * tid);
      h2_t p; p.x = (_Float16)v0.x; p.y = (_Float16)v0.y;
      xs2[0][tid] = __builtin_bit_cast(uint32_t, p);
      float2 v1 = *(const float2*)(xb + (size_t)tq1 * D_ + 2 * tid);
      xpend.x = (_Float16)v1.x; xpend.y = (_Float16)v1.y;
    }
  }
  __syncthreads();

  auto step = [&](int tt, int par, h2_t& xwreg) {
    const int t = dir ? (T_ - 1 - tt) : tt;
    float a0, a1, b0, b1;
    if (USE_XW) {
      a0 = bias0 + (float)xwreg.x;
      b0 = bias1 + (float)xwreg.y;
      a1 = 0.f; b1 = 0.f;
      const int ttc = (tt + 2 < T_) ? (tt + 2) : (T_ - 1);
      const int tq2 = dir ? (T_ - 1 - ttc) : ttc;
      xwreg = xwb[(size_t)tq2 * 256 + tid];     // prefetch; waited 2 steps later
    } else {
      a0 = bias0; a1 = 0.f; b0 = bias1; b1 = 0.f;
      if (tid < 40) {
        xs2[par ^ 1][tid] = __builtin_bit_cast(uint32_t, xpend);  // x for tt+1
        const int ttc = (tt + 2 < T_) ? (tt + 2) : (T_ - 1);
        const int tq2 = dir ? (T_ - 1 - ttc) : ttc;
        float2 v = *(const float2*)(xb + (size_t)tq2 * D_ + 2 * tid);
        xpend.x = (_Float16)v.x; xpend.y = (_Float16)v.y;
      }
      uint32_t xreg = xs2[par][lane];
      #pragma unroll
      for (int j = 0; j < 40; j += 2) {
        h2_t xv0 = asH2u_(lanebu_(xreg, j));
        h2_t xv1 = asH2u_(lanebu_(xreg, j + 1));
        a0 = fdot2_(wx0[j],     xv0, a0); b0 = fdot2_(wx1[j],     xv0, b0);
        a1 = fdot2_(wx0[j + 1], xv1, a1); b1 = fdot2_(wx1[j + 1], xv1, b1);
      }
    }

    const uint32_t h2reg = ((const uint32_t*)hsf[par])[lane];
    #pragma unroll
    for (int j = 0; j < 64; j += 2) {
      h2_t hv0 = asH2u_(lanebu_(h2reg, j));
      h2_t hv1 = asH2u_(lanebu_(h2reg, j + 1));
      a0 = fdot2_(w0[j],     hv0, a0); b0 = fdot2_(w1[j],     hv0, b0);
      a1 = fdot2_(w0[j + 1], hv1, a1); b1 = fdot2_(w1[j + 1], hv1, b1);
    }
    const float ga = a0 + a1;   // i (role0) or f (role1)
    const float gb = b0 + b1;   // g (role0) or o (role1)

    float p = 0.f, sf = 0.f, so = 0.f;
    if (role == 0) p = sigf_(ga) * tanhf_(gb);
    else { sf = sigf_(ga); so = sigf_(gb); }
    const float ex = __shfl_xor(p, 1);          // role0 -> role1, same unit
    if (role) {
      c = sf * c + ex;
      const float h = so * tanhf_(c);
      hsf[par ^ 1][unit] = (_Float16)h;
      hb[(size_t)t * (2 * H_) + unit] = (_Float16)h;  // never drained in-loop
    }
    barrier_lds_();
  };

  for (int tb = 0; tb < T_; tb += 2) {
    step(tb,     0, xwA);
    step(tb + 1, 1, xwB);
  }
}

// ---------------------------------------------------------------------------
// Emissions from f16 hcat. 64 bt-rows per block; h tile in LDS (stride 257),
// Wp in LDS (wave-uniform broadcast).
// ---------------------------------------------------------------------------
__global__ __launch_bounds__(256)
void emis_kernel(const _Float16* __restrict__ hcat,
                 const float* __restrict__ Wp, const float* __restrict__ bp,
                 float* __restrict__ em)
{
  __shared__ float sh[64 * 257];
  __shared__ float swp[40 * 256];
  const int tid = threadIdx.x;

  for (int i = tid; i < K_ * 256; i += 256) swp[i] = Wp[i];

  const h2_t* src = (const h2_t*)(hcat + (size_t)blockIdx.x * 64 * 256);
  for (int i = tid; i < 64 * 128; i += 256) {
    h2_t v = src[i];
    int row = i >> 7, col = (i & 127) * 2;
    sh[row * 257 + col]     = (float)v.x;
    sh[row * 257 + col + 1] = (float)v.y;
  }
  __syncthreads();

  const int row = tid & 63;
  const int kq  = tid >> 6;          // wave-uniform
  const float* hrow = &sh[row * 257];

  float accs[10];
  #pragma unroll
  for (int q = 0; q < 10; ++q) {
    int k = kq * 10 + q;
    accs[q] = (k < K_) ? bp[k] : 0.0f;
  }

  for (int j0 = 0; j0 < 256; j0 += 4) {
    float h0 = hrow[j0], h1 = hrow[j0 + 1], hh2 = hrow[j0 + 2], h3 = hrow[j0 + 3];
    #pragma unroll
    for (int q = 0; q < 10; ++q) {
      const float4 w = *(const float4*)&swp[(kq * 10 + q) * 256 + j0];
      accs[q] += h0 * w.x + h1 * w.y + hh2 * w.z + h3 * w.w;
    }
  }

  const size_t bt = (size_t)blockIdx.x * 64 + row;
  #pragma unroll
  for (int q = 0; q < 10; ++q) {
    int k = kq * 10 + q;
    if (k < K_) em[bt * K_ + k] = accs[q];
  }
}

// ---------------------------------------------------------------------------
// Numerator: masked reduction over t per batch element.
// ---------------------------------------------------------------------------
__global__ void crf_num_kernel(const int* __restrict__ labels, const int* __restrict__ lengths,
                               const float* __restrict__ em,
                               const float* __restrict__ start_t, const float* __restrict__ end_t,
                               const float* __restrict__ trans,
                               float* __restrict__ num)
{
  const int b = blockIdx.x;
  const int tid = threadIdx.x;   // 256
  const int len = lengths[b];
  float acc = 0.0f;
  for (int t = 1 + tid; t < len; t += 256) {
    int lp = labels[b * T_ + t - 1];
    int lc = labels[b * T_ + t];
    acc += trans[lp * K_ + lc] + em[((size_t)b * T_ + t) * K_ + lc];
  }
  __shared__ float red[256];
  red[tid] = acc;
  __syncthreads();
  for (int s = 128; s > 0; s >>= 1) {
    if (tid < s) red[tid] += red[tid + s];
    __syncthreads();
  }
  if (tid == 0) {
    int l0 = labels[b * T_];
    int ll = labels[b * T_ + len - 1];
    num[b] = red[0] + start_t[l0] + em[(size_t)b * T_ * K_ + l0] + end_t[ll];
  }
}

// ---------------------------------------------------------------------------
// Denominator: linear-space forward algorithm, one wave per batch element.
// et column register-resident; per step 39 readlane-FMA + 1 exp; em
// prefetched 4 steps ahead; renormalize every 4 steps.
// ---------------------------------------------------------------------------
__global__ void crf_den_kernel(const float* __restrict__ em, const int* __restrict__ lengths,
                               const float* __restrict__ start_t, const float* __restrict__ end_t,
                               const float* __restrict__ trans,
                               float* __restrict__ den)
{
  const int b = blockIdx.x;
  const int k = threadIdx.x;     // 64 threads = 1 wave

  float et[K_];
  #pragma unroll
  for (int j = 0; j < K_; ++j)
    et[j] = (k < K_) ? __expf(trans[j * K_ + k]) : 0.0f;

  const int len = lengths[b];
  const float* emb = em + (size_t)b * T_ * K_;

  float a0 = (k < K_) ? (start_t[k] + emb[k]) : -1e30f;
  float m = a0;
  #pragma unroll
  for (int off = 32; off > 0; off >>= 1) m = fmaxf(m, __shfl_xor(m, off));
  float v = __expf(a0 - m);           // lanes >= 39 -> 0
  float off_acc = m;

  auto ld = [&](int t) -> float {
    int tc = (t < len) ? t : (len - 1);
    return (k < K_) ? emb[(size_t)tc * K_ + k] : 0.0f;
  };
  float e0 = ld(1), e1 = ld(2), e2 = ld(3), e3 = ld(4);

  for (int t = 1; t < len; ++t) {
    const float emc = e0;
    e0 = e1; e1 = e2; e2 = e3;
    e3 = ld(t + 4);

    const float pv = v;
    float s0 = 0.f, s1 = 0.f, s2 = 0.f, s3 = 0.f;
    #pragma unroll
    for (int j = 0; j < 36; j += 4) {
      s0 = fmaf(laneb_(pv, j),     et[j],     s0);
      s1 = fmaf(laneb_(pv, j + 1), et[j + 1], s1);
      s2 = fmaf(laneb_(pv, j + 2), et[j + 2], s2);
      s3 = fmaf(laneb_(pv, j + 3), et[j + 3], s3);
    }
    s0 = fmaf(laneb_(pv, 36), et[36], s0);
    s1 = fmaf(laneb_(pv, 37), et[37], s1);
    s2 = fmaf(laneb_(pv, 38), et[38], s2);

    v = ((s0 + s1) + (s2 + s3)) * __expf(emc);
    if ((t & 3) == 0) {
      float vm = v;
      #pragma unroll
      for (int off = 32; off > 0; off >>= 1) vm = fmaxf(vm, __shfl_xor(vm, off));
      v *= 1.0f / vm;
      off_acc += __logf(vm);
    }
  }

  float w = (k < K_) ? v * __expf(end_t[k]) : 0.0f;
  #pragma unroll
  for (int off = 32; off > 0; off >>= 1) w += __shfl_xor(w, off);
  if (k == 0) den[b] = off_acc + __logf(w);
}

__global__ void finalize_kernel(const float* __restrict__ num, const float* __restrict__ den,
                                float* __restrict__ out)
{
  const int tid = threadIdx.x;   // 64
  float v = den[tid] - num[tid];
  #pragma unroll
  for (int off = 32; off > 0; off >>= 1) v += __shfl_down(v, off);
  if (tid == 0) out[0] = v * (1.0f / 64.0f);
}

extern "C" void kernel_launch(void* const* d_in, const int* in_sizes, int n_in,
                              void* d_out, int out_size, void* d_ws, size_t ws_size,
                              hipStream_t stream)
{
  (void)in_sizes; (void)n_in; (void)out_size;
  const float* features = (const float*)d_in[0];
  const int*   lengths  = (const int*)d_in[1];
  const int*   labels   = (const int*)d_in[2];
  const float* Wih_f = (const float*)d_in[3];
  const float* Whh_f = (const float*)d_in[4];
  const float* bih_f = (const float*)d_in[5];
  const float* bhh_f = (const float*)d_in[6];
  const float* Wih_b = (const float*)d_in[7];
  const float* Whh_b = (const float*)d_in[8];
  const float* bih_b = (const float*)d_in[9];
  const float* bhh_b = (const float*)d_in[10];
  const float* Wp      = (const float*)d_in[11];
  const float* bp      = (const float*)d_in[12];
  const float* start_t = (const float*)d_in[13];
  const float* end_t   = (const float*)d_in[14];
  const float* trans   = (const float*)d_in[15];
  float* out = (float*)d_out;

  // ws layout (bytes): hcat f16 [0, 26214400) ; em f32 [26214400, +7987200) ;
  // num/den 512 B ; xwp h2 [34202112, +104857600) if ws is big enough.
  char* wsc = (char*)d_ws;
  _Float16* hcatH = (_Float16*)wsc;
  float*    em    = (float*)(wsc + 26214400);
  float*    num   = (float*)(wsc + 26214400 + 7987200);
  float*    den   = num + B_;
  h2_t*     xwp   = (h2_t*)(wsc + 34202112);
  const bool big  = ws_size >= (size_t)34202112 + 104857600;

  if (big) {
    hipLaunchKernelGGL(xw_kernel, dim3(B_ * T_ / 256), dim3(256), 0, stream,
                       features, Wih_f, Wih_b, xwp);
    hipLaunchKernelGGL((lstm_kernel<1>), dim3(2 * B_), dim3(256), 0, stream,
                       features, Wih_f, Whh_f, bih_f, bhh_f,
                       Wih_b, Whh_b, bih_b, bhh_b, xwp, hcatH);
  } else {
    hipLaunchKernelGGL((lstm_kernel<0>), dim3(2 * B_), dim3(256), 0, stream,
                       features, Wih_f, Whh_f, bih_f, bhh_f,
                       Wih_b, Whh_b, bih_b, bhh_b, xwp, hcatH);
  }
  hipLaunchKernelGGL(emis_kernel, dim3(B_ * T_ / 64), dim3(256), 0, stream,
                     hcatH, Wp, bp, em);
  hipLaunchKernelGGL(crf_num_kernel, dim3(B_), dim3(256), 0, stream,
                     labels, lengths, em, start_t, end_t, trans, num);
  hipLaunchKernelGGL(crf_den_kernel, dim3(B_), dim3(64), 0, stream,
                     em, lengths, start_t, end_t, trans, den);
  hipLaunchKernelGGL(finalize_kernel, dim3(1), dim3(64), 0, stream,
                     num, den, out);
}

// Round 8
// 1001.463 us; speedup vs baseline: 1.0677x; 1.0677x over previous
//
#include <hip/hip_runtime.h>
#include <cstddef>
#include <cstdint>

#define B_ 64
#define T_ 800
#define D_ 80
#define H_ 128
#define K_ 39
#define BT_ (B_ * T_)   // 51200

typedef _Float16 h2_t  __attribute__((ext_vector_type(2)));
typedef _Float16 f16x8 __attribute__((ext_vector_type(8)));
typedef float    f32x4 __attribute__((ext_vector_type(4)));

__device__ __forceinline__ float fdot2_(h2_t a, h2_t b, float c) {
#if __has_builtin(__builtin_amdgcn_fdot2)
  return __builtin_amdgcn_fdot2(a, b, c, false);
#else
  return c + (float)a.x * (float)b.x + (float)a.y * (float)b.y;
#endif
}

__device__ __forceinline__ h2_t asH2u_(uint32_t u) { return __builtin_bit_cast(h2_t, u); }

__device__ __forceinline__ float sigf_(float x)  { return 1.0f / (1.0f + __expf(-x)); }
__device__ __forceinline__ float tanhf_(float x) { return 2.0f / (1.0f + __expf(-2.0f * x)) - 1.0f; }

__device__ __forceinline__ float laneb_(float v, int lane) {
  return __builtin_bit_cast(float, __builtin_amdgcn_readlane(__builtin_bit_cast(int, v), lane));
}
__device__ __forceinline__ uint32_t lanebu_(uint32_t v, int lane) {
  return (uint32_t)__builtin_amdgcn_readlane((int)v, lane);
}

// LDS-only barrier: waits LDS ops but does NOT drain vmem (HIP __syncthreads
// emits s_waitcnt vmcnt(0) which serializes prefetch/store pipelines).
__device__ __forceinline__ void barrier_lds_() {
  asm volatile("s_waitcnt lgkmcnt(0)" ::: "memory");
  __builtin_amdgcn_s_barrier();
}

// lstm lane->gate-rows mapping: wave w, lane L: unit = w*32 + (L>>1),
// role = L&1. role0 owns (i,g) rows, role1 owns (f,o). shfl_xor(1) pairs.
__device__ __forceinline__ void rows_of_(int tid, int& unit, int& role, int& r0, int& r1) {
  const int w = tid >> 6, L = tid & 63;
  unit = w * 32 + (L >> 1);
  role = L & 1;
  r0 = role * H_ + unit;            // i (role0) or f (role1)
  r1 = 2 * H_ + role * H_ + unit;   // g (role0) or o (role1)
}

// ---------------------------------------------------------------------------
// xw via MFMA 16x16x32 f16:  xw[dir][bt][512] = x[bt][0:80] . Wih_dir^T
// Grid 200: dir = blockIdx&1, m-chunk of 512 bt rows = blockIdx>>1.
// Wave w owns gate cols [w*128, w*128+128): B-frags (Wih^T) register-resident
// (8 ntiles x 3 ktiles, K padded 80->96). x staged in LDS f16 (pad zeroed).
// A-layout: A[m=lane&15][k=quad*8+j]; B: B[k=quad*8+j][n=lane&15];
// D: col=lane&15, row=quad*4+reg (verified mappings, guide §3).
// ---------------------------------------------------------------------------
__global__ __launch_bounds__(256, 1)
void xw_kernel(const float* __restrict__ x,
               const float* __restrict__ Wih_f, const float* __restrict__ Wih_b,
               _Float16* __restrict__ xw)
{
  const int dir = blockIdx.x & 1;
  const int mc  = blockIdx.x >> 1;           // 0..99
  const float* W = dir ? Wih_b : Wih_f;

  const int tid  = threadIdx.x;
  const int w    = tid >> 6;
  const int lane = tid & 63;
  const int lm   = lane & 15;
  const int quad = lane >> 4;

  // B preload: frag[nt][kt], lane holds Wih[w*128+nt*16+lm][kt*32+quad*8 + j]
  f16x8 Bf[8][3];
  #pragma unroll
  for (int nt = 0; nt < 8; ++nt) {
    const int r = w * 128 + nt * 16 + lm;
    #pragma unroll
    for (int kt = 0; kt < 3; ++kt) {
      const int kb = kt * 32 + quad * 8;
      #pragma unroll
      for (int j = 0; j < 8; ++j) {
        const int k = kb + j;
        Bf[nt][kt][j] = (k < D_) ? (_Float16)W[(size_t)r * D_ + k] : (_Float16)0.0f;
      }
    }
  }

  __shared__ alignas(16) _Float16 xs[128 * 96];   // 24 KB, K padded to 96
  for (int i = tid; i < 128 * 96; i += 256) xs[i] = (_Float16)0.0f;

  for (int cc = 0; cc < 4; ++cc) {
    const int base = mc * 512 + cc * 128;
    __syncthreads();   // pad/previous compute done
    {
      const float4* src = (const float4*)(x + (size_t)base * D_);
      for (int i = tid; i < 128 * D_ / 4; i += 256) {
        float4 v = src[i];
        const int row = i / 20, col = (i % 20) * 4;
        h2_t p0, p1;
        p0.x = (_Float16)v.x; p0.y = (_Float16)v.y;
        p1.x = (_Float16)v.z; p1.y = (_Float16)v.w;
        uint2 pk;
        pk.x = __builtin_bit_cast(uint32_t, p0);
        pk.y = __builtin_bit_cast(uint32_t, p1);
        *(uint2*)&xs[row * 96 + col] = pk;
      }
    }
    __syncthreads();

    #pragma unroll
    for (int mt = 0; mt < 8; ++mt) {
      f16x8 Af[3];
      #pragma unroll
      for (int kt = 0; kt < 3; ++kt)
        Af[kt] = *(const f16x8*)&xs[(mt * 16 + lm) * 96 + kt * 32 + quad * 8];

      f32x4 acc[8];
      #pragma unroll
      for (int nt = 0; nt < 8; ++nt) acc[nt] = (f32x4){0.f, 0.f, 0.f, 0.f};
      #pragma unroll
      for (int kt = 0; kt < 3; ++kt)
        #pragma unroll
        for (int nt = 0; nt < 8; ++nt)
          acc[nt] = __builtin_amdgcn_mfma_f32_16x16x32_f16(Af[kt], Bf[nt][kt], acc[nt], 0, 0, 0);

      _Float16* outb = xw + ((size_t)dir * BT_ + base + mt * 16) * 512;
      #pragma unroll
      for (int nt = 0; nt < 8; ++nt) {
        const int col = w * 128 + nt * 16 + lm;
        #pragma unroll
        for (int rg = 0; rg < 4; ++rg) {
          const int row = quad * 4 + rg;
          outb[(size_t)row * 512 + col] = (_Float16)acc[nt][rg];
        }
      }
    }
  }
}

// ---------------------------------------------------------------------------
// Recurrent LSTM. Grid 128 (one WG per (b,dir)), 256 threads.
// h broadcast via readlane (1 ds_read_b32/wave/step), LDS-only barrier,
// double-buffered h by parity. Whh f16x2 register-resident (128 VGPRs).
// xw (plain layout) loads and h stores batched per 8-step block: loads
// issued BEFORE stores so vmcnt waits for loads never wait on stores.
// ---------------------------------------------------------------------------
template<int USE_XW>
__global__ __launch_bounds__(256, 1)
void lstm_kernel(const float* __restrict__ x,
                 const float* __restrict__ Wih_f, const float* __restrict__ Whh_f,
                 const float* __restrict__ bih_f, const float* __restrict__ bhh_f,
                 const float* __restrict__ Wih_b, const float* __restrict__ Whh_b,
                 const float* __restrict__ bih_b, const float* __restrict__ bhh_b,
                 const _Float16* __restrict__ xw,
                 _Float16* __restrict__ hcat)
{
  const int bb  = blockIdx.x & 63;
  const int dir = blockIdx.x >> 6;
  const float* Whh = dir ? Whh_b : Whh_f;
  const float* Wih = dir ? Wih_b : Wih_f;
  const float* bih = dir ? bih_b : bih_f;
  const float* bhh = dir ? bhh_b : bhh_f;

  const int tid  = threadIdx.x;
  const int lane = tid & 63;
  int unit, role, r0, r1; rows_of_(tid, unit, role, r0, r1);

  h2_t w0[64], w1[64];
  #pragma unroll
  for (int j = 0; j < 64; ++j) {
    float2 a = *(const float2*)(Whh + (size_t)r0 * H_ + 2 * j);
    float2 d = *(const float2*)(Whh + (size_t)r1 * H_ + 2 * j);
    w0[j].x = (_Float16)a.x; w0[j].y = (_Float16)a.y;
    w1[j].x = (_Float16)d.x; w1[j].y = (_Float16)d.y;
  }
  h2_t wx0[40], wx1[40];
  if (!USE_XW) {
    #pragma unroll
    for (int i = 0; i < 40; ++i) {
      float2 a = *(const float2*)(Wih + (size_t)r0 * D_ + 2 * i);
      float2 d = *(const float2*)(Wih + (size_t)r1 * D_ + 2 * i);
      wx0[i].x = (_Float16)a.x; wx0[i].y = (_Float16)a.y;
      wx1[i].x = (_Float16)d.x; wx1[i].y = (_Float16)d.y;
    }
  }
  const float bias0 = bih[r0] + bhh[r0];
  const float bias1 = bih[r1] + bhh[r1];

  __shared__ alignas(8) _Float16 hsf[2][H_];   // double-buffered h
  __shared__ uint32_t xs2[2][64];              // fallback x staging

  if (tid < H_) hsf[0][tid] = (_Float16)0.0f;
  if (!USE_XW && tid < 64) { xs2[0][tid] = 0u; xs2[1][tid] = 0u; }
  float c = 0.0f;   // role1 owns cell state of its unit
  _Float16 hbuf[8];

  const _Float16* xwd = xw + (size_t)dir * BT_ * 512 + (size_t)bb * T_ * 512;
  const float*    xb  = x + (size_t)bb * T_ * D_;
  _Float16*       hb  = hcat + (size_t)bb * T_ * (2 * H_) + dir * H_;

  _Float16 xc0[8], xc1[8], xn0[8], xn1[8];
  h2_t xpend; xpend.x = (_Float16)0.f; xpend.y = (_Float16)0.f;

  if (USE_XW) {
    #pragma unroll
    for (int q = 0; q < 8; ++q) {
      const int t = dir ? (T_ - 1 - q) : q;
      xc0[q] = xwd[(size_t)t * 512 + r0];
      xc1[q] = xwd[(size_t)t * 512 + r1];
    }
  } else {
    const int tq0 = dir ? (T_ - 1) : 0;
    const int tq1 = dir ? (T_ - 2) : 1;
    if (tid < 40) {
      float2 v0 = *(const float2*)(xb + (size_t)tq0 * D_ + 2 * tid);
      h2_t p; p.x = (_Float16)v0.x; p.y = (_Float16)v0.y;
      xs2[0][tid] = __builtin_bit_cast(uint32_t, p);
      float2 v1 = *(const float2*)(xb + (size_t)tq1 * D_ + 2 * tid);
      xpend.x = (_Float16)v1.x; xpend.y = (_Float16)v1.y;
    }
  }
  __syncthreads();

  auto step = [&](int tt, int q, int par, const _Float16 xv0, const _Float16 xv1) {
    const int t = dir ? (T_ - 1 - tt) : tt;
    float a0, a1, b0, b1;
    if (USE_XW) {
      a0 = bias0 + (float)xv0;
      b0 = bias1 + (float)xv1;
      a1 = 0.f; b1 = 0.f;
    } else {
      a0 = bias0; a1 = 0.f; b0 = bias1; b1 = 0.f;
      if (tid < 40) {
        xs2[par ^ 1][tid] = __builtin_bit_cast(uint32_t, xpend);
        const int ttc = (tt + 2 < T_) ? (tt + 2) : (T_ - 1);
        const int tq2 = dir ? (T_ - 1 - ttc) : ttc;
        float2 v = *(const float2*)(xb + (size_t)tq2 * D_ + 2 * tid);
        xpend.x = (_Float16)v.x; xpend.y = (_Float16)v.y;
      }
      uint32_t xreg = xs2[par][lane];
      #pragma unroll
      for (int j = 0; j < 40; j += 2) {
        h2_t q0 = asH2u_(lanebu_(xreg, j));
        h2_t q1 = asH2u_(lanebu_(xreg, j + 1));
        a0 = fdot2_(wx0[j],     q0, a0); b0 = fdot2_(wx1[j],     q0, b0);
        a1 = fdot2_(wx0[j + 1], q1, a1); b1 = fdot2_(wx1[j + 1], q1, b1);
      }
    }

    const uint32_t h2reg = ((const uint32_t*)hsf[par])[lane];
    #pragma unroll
    for (int j = 0; j < 64; j += 2) {
      h2_t hv0 = asH2u_(lanebu_(h2reg, j));
      h2_t hv1 = asH2u_(lanebu_(h2reg, j + 1));
      a0 = fdot2_(w0[j],     hv0, a0); b0 = fdot2_(w1[j],     hv0, b0);
      a1 = fdot2_(w0[j + 1], hv1, a1); b1 = fdot2_(w1[j + 1], hv1, b1);
    }
    const float ga = a0 + a1;   // i (role0) or f (role1)
    const float gb = b0 + b1;   // g (role0) or o (role1)

    float p = 0.f, sf = 0.f, so = 0.f;
    if (role == 0) p = sigf_(ga) * tanhf_(gb);
    else { sf = sigf_(ga); so = sigf_(gb); }
    const float ex = __shfl_xor(p, 1);
    if (role) {
      c = sf * c + ex;
      const float h = so * tanhf_(c);
      hsf[par ^ 1][unit] = (_Float16)h;
      hbuf[q] = (_Float16)h;
    }
    barrier_lds_();
  };

  for (int bbk = 0; bbk < 100; ++bbk) {
    const int tb = bbk * 8;
    // 1) prefetch next block's xw (loads issued BEFORE the stores below)
    if (USE_XW && bbk + 1 < 100) {
      #pragma unroll
      for (int q = 0; q < 8; ++q) {
        const int tt = tb + 8 + q;
        const int t  = dir ? (T_ - 1 - tt) : tt;
        xn0[q] = xwd[(size_t)t * 512 + r0];
        xn1[q] = xwd[(size_t)t * 512 + r1];
      }
    }
    // 2) flush previous block's h stores (have 8 steps to drain)
    if (role && bbk > 0) {
      #pragma unroll
      for (int q = 0; q < 8; ++q) {
        const int ts = tb - 8 + q;
        const int tq = dir ? (T_ - 1 - ts) : ts;
        hb[(size_t)tq * (2 * H_) + unit] = hbuf[q];
      }
    }
    // 3) 8 steps
    #pragma unroll
    for (int q = 0; q < 8; ++q)
      step(tb + q, q, q & 1, xc0[q], xc1[q]);
    // 4) rotate prefetch regs
    if (USE_XW) {
      #pragma unroll
      for (int q = 0; q < 8; ++q) { xc0[q] = xn0[q]; xc1[q] = xn1[q]; }
    }
  }
  if (role) {
    #pragma unroll
    for (int q = 0; q < 8; ++q) {
      const int ts = T_ - 8 + q;
      const int tq = dir ? (T_ - 1 - ts) : ts;
      hb[(size_t)tq * (2 * H_) + unit] = hbuf[q];
    }
  }
}

// ---------------------------------------------------------------------------
// Emissions via MFMA: em[bt][39] = hcat[bt][0:256] . Wp^T + bp.
// B-frags (Wp^T, N padded 39->48, K=256) register-resident per wave (24 frags);
// A-frags loaded directly from global hcat (contiguous 16B). Each wave does
// 4 independent m-tiles; grid 200.
// ---------------------------------------------------------------------------
__global__ __launch_bounds__(256, 1)
void emis_kernel(const _Float16* __restrict__ hcat,
                 const float* __restrict__ Wp, const float* __restrict__ bp,
                 float* __restrict__ em)
{
  const int tid  = threadIdx.x;
  const int w    = tid >> 6;
  const int lane = tid & 63;
  const int lm   = lane & 15;
  const int quad = lane >> 4;

  f16x8 Bf[3][8];
  float bias[3];
  #pragma unroll
  for (int nt = 0; nt < 3; ++nt) {
    const int n = nt * 16 + lm;
    const bool valid = n < K_;
    bias[nt] = valid ? bp[n] : 0.0f;
    #pragma unroll
    for (int kt = 0; kt < 8; ++kt) {
      const int kb = kt * 32 + quad * 8;
      #pragma unroll
      for (int j = 0; j < 8; ++j)
        Bf[nt][kt][j] = valid ? (_Float16)Wp[(size_t)n * 256 + kb + j] : (_Float16)0.0f;
    }
  }

  #pragma unroll
  for (int q = 0; q < 4; ++q) {
    const int mt  = blockIdx.x * 16 + w * 4 + q;
    const int bt0 = mt * 16;

    f16x8 Af[8];
    const _Float16* ab = hcat + ((size_t)bt0 + lm) * 256;
    #pragma unroll
    for (int kt = 0; kt < 8; ++kt)
      Af[kt] = *(const f16x8*)(ab + kt * 32 + quad * 8);

    f32x4 acc[3];
    #pragma unroll
    for (int nt = 0; nt < 3; ++nt) acc[nt] = (f32x4){0.f, 0.f, 0.f, 0.f};
    #pragma unroll
    for (int kt = 0; kt < 8; ++kt)
      #pragma unroll
      for (int nt = 0; nt < 3; ++nt)
        acc[nt] = __builtin_amdgcn_mfma_f32_16x16x32_f16(Af[kt], Bf[nt][kt], acc[nt], 0, 0, 0);

    #pragma unroll
    for (int nt = 0; nt < 3; ++nt) {
      const int n = nt * 16 + lm;
      if (n < K_) {
        #pragma unroll
        for (int rg = 0; rg < 4; ++rg) {
          const int row = bt0 + quad * 4 + rg;
          em[(size_t)row * K_ + n] = acc[nt][rg] + bias[nt];
        }
      }
    }
  }
}

// ---------------------------------------------------------------------------
// Numerator: masked reduction over t per batch element.
// ---------------------------------------------------------------------------
__global__ void crf_num_kernel(const int* __restrict__ labels, const int* __restrict__ lengths,
                               const float* __restrict__ em,
                               const float* __restrict__ start_t, const float* __restrict__ end_t,
                               const float* __restrict__ trans,
                               float* __restrict__ num)
{
  const int b = blockIdx.x;
  const int tid = threadIdx.x;   // 256
  const int len = lengths[b];
  float acc = 0.0f;
  for (int t = 1 + tid; t < len; t += 256) {
    int lp = labels[b * T_ + t - 1];
    int lc = labels[b * T_ + t];
    acc += trans[lp * K_ + lc] + em[((size_t)b * T_ + t) * K_ + lc];
  }
  __shared__ float red[256];
  red[tid] = acc;
  __syncthreads();
  for (int s = 128; s > 0; s >>= 1) {
    if (tid < s) red[tid] += red[tid + s];
    __syncthreads();
  }
  if (tid == 0) {
    int l0 = labels[b * T_];
    int ll = labels[b * T_ + len - 1];
    num[b] = red[0] + start_t[l0] + em[(size_t)b * T_ * K_ + l0] + end_t[ll];
  }
}

// ---------------------------------------------------------------------------
// Denominator: linear-space forward algorithm, one wave per batch element.
// (Unchanged this round — diagnostic control for the "other 486 us" bucket.)
// ---------------------------------------------------------------------------
__global__ void crf_den_kernel(const float* __restrict__ em, const int* __restrict__ lengths,
                               const float* __restrict__ start_t, const float* __restrict__ end_t,
                               const float* __restrict__ trans,
                               float* __restrict__ den)
{
  const int b = blockIdx.x;
  const int k = threadIdx.x;     // 64 threads = 1 wave

  float et[K_];
  #pragma unroll
  for (int j = 0; j < K_; ++j)
    et[j] = (k < K_) ? __expf(trans[j * K_ + k]) : 0.0f;

  const int len = lengths[b];
  const float* emb = em + (size_t)b * T_ * K_;

  float a0 = (k < K_) ? (start_t[k] + emb[k]) : -1e30f;
  float m = a0;
  #pragma unroll
  for (int off = 32; off > 0; off >>= 1) m = fmaxf(m, __shfl_xor(m, off));
  float v = __expf(a0 - m);
  float off_acc = m;

  auto ld = [&](int t) -> float {
    int tc = (t < len) ? t : (len - 1);
    return (k < K_) ? emb[(size_t)tc * K_ + k] : 0.0f;
  };
  float e0 = ld(1), e1 = ld(2), e2 = ld(3), e3 = ld(4);

  for (int t = 1; t < len; ++t) {
    const float emc = e0;
    e0 = e1; e1 = e2; e2 = e3;
    e3 = ld(t + 4);

    const float pv = v;
    float s0 = 0.f, s1 = 0.f, s2 = 0.f, s3 = 0.f;
    #pragma unroll
    for (int j = 0; j < 36; j += 4) {
      s0 = fmaf(laneb_(pv, j),     et[j],     s0);
      s1 = fmaf(laneb_(pv, j + 1), et[j + 1], s1);
      s2 = fmaf(laneb_(pv, j + 2), et[j + 2], s2);
      s3 = fmaf(laneb_(pv, j + 3), et[j + 3], s3);
    }
    s0 = fmaf(laneb_(pv, 36), et[36], s0);
    s1 = fmaf(laneb_(pv, 37), et[37], s1);
    s2 = fmaf(laneb_(pv, 38), et[38], s2);

    v = ((s0 + s1) + (s2 + s3)) * __expf(emc);
    if ((t & 3) == 0) {
      float vm = v;
      #pragma unroll
      for (int off = 32; off > 0; off >>= 1) vm = fmaxf(vm, __shfl_xor(vm, off));
      v *= 1.0f / vm;
      off_acc += __logf(vm);
    }
  }

  float w = (k < K_) ? v * __expf(end_t[k]) : 0.0f;
  #pragma unroll
  for (int off = 32; off > 0; off >>= 1) w += __shfl_xor(w, off);
  if (k == 0) den[b] = off_acc + __logf(w);
}

__global__ void finalize_kernel(const float* __restrict__ num, const float* __restrict__ den,
                                float* __restrict__ out)
{
  const int tid = threadIdx.x;   // 64
  float v = den[tid] - num[tid];
  #pragma unroll
  for (int off = 32; off > 0; off >>= 1) v += __shfl_down(v, off);
  if (tid == 0) out[0] = v * (1.0f / 64.0f);
}

extern "C" void kernel_launch(void* const* d_in, const int* in_sizes, int n_in,
                              void* d_out, int out_size, void* d_ws, size_t ws_size,
                              hipStream_t stream)
{
  (void)in_sizes; (void)n_in; (void)out_size;
  const float* features = (const float*)d_in[0];
  const int*   lengths  = (const int*)d_in[1];
  const int*   labels   = (const int*)d_in[2];
  const float* Wih_f = (const float*)d_in[3];
  const float* Whh_f = (const float*)d_in[4];
  const float* bih_f = (const float*)d_in[5];
  const float* bhh_f = (const float*)d_in[6];
  const float* Wih_b = (const float*)d_in[7];
  const float* Whh_b = (const float*)d_in[8];
  const float* bih_b = (const float*)d_in[9];
  const float* bhh_b = (const float*)d_in[10];
  const float* Wp      = (const float*)d_in[11];
  const float* bp      = (const float*)d_in[12];
  const float* start_t = (const float*)d_in[13];
  const float* end_t   = (const float*)d_in[14];
  const float* trans   = (const float*)d_in[15];
  float* out = (float*)d_out;

  // ws layout (bytes): hcat f16 [0, 26214400) ; em f32 [26214400, +7987200) ;
  // num/den 512 B ; xw f16 [34202112, +104857600) if ws is big enough.
  char* wsc = (char*)d_ws;
  _Float16* hcatH = (_Float16*)wsc;
  float*    em    = (float*)(wsc + 26214400);
  float*    num   = (float*)(wsc + 26214400 + 7987200);
  float*    den   = num + B_;
  _Float16* xwH   = (_Float16*)(wsc + 34202112);
  const bool big  = ws_size >= (size_t)34202112 + 104857600;

  if (big) {
    hipLaunchKernelGGL(xw_kernel, dim3(200), dim3(256), 0, stream,
                       features, Wih_f, Wih_b, xwH);
    hipLaunchKernelGGL((lstm_kernel<1>), dim3(2 * B_), dim3(256), 0, stream,
                       features, Wih_f, Whh_f, bih_f, bhh_f,
                       Wih_b, Whh_b, bih_b, bhh_b, xwH, hcatH);
  } else {
    hipLaunchKernelGGL((lstm_kernel<0>), dim3(2 * B_), dim3(256), 0, stream,
                       features, Wih_f, Whh_f, bih_f, bhh_f,
                       Wih_b, Whh_b, bih_b, bhh_b, xwH, hcatH);
  }
  hipLaunchKernelGGL(emis_kernel, dim3(BT_ / 256), dim3(256), 0, stream,
                     hcatH, Wp, bp, em);
  hipLaunchKernelGGL(crf_num_kernel, dim3(B_), dim3(256), 0, stream,
                     labels, lengths, em, start_t, end_t, trans, num);
  hipLaunchKernelGGL(crf_den_kernel, dim3(B_), dim3(64), 0, stream,
                     em, lengths, start_t, end_t, trans, den);
  hipLaunchKernelGGL(finalize_kernel, dim3(1), dim3(64), 0, stream,
                     num, den, out);
}

// Round 9
// 875.977 us; speedup vs baseline: 1.2207x; 1.1433x over previous
//
#include <hip/hip_runtime.h>
#include <cstddef>
#include <cstdint>

#define B_ 64
#define T_ 800
#define D_ 80
#define H_ 128
#define K_ 39
#define BT_ (B_ * T_)   // 51200

typedef _Float16 h2_t  __attribute__((ext_vector_type(2)));
typedef _Float16 f16x8 __attribute__((ext_vector_type(8)));
typedef float    f32x4 __attribute__((ext_vector_type(4)));

__device__ __forceinline__ float fdot2_(h2_t a, h2_t b, float c) {
#if __has_builtin(__builtin_amdgcn_fdot2)
  return __builtin_amdgcn_fdot2(a, b, c, false);
#else
  return c + (float)a.x * (float)b.x + (float)a.y * (float)b.y;
#endif
}

__device__ __forceinline__ h2_t asH2u_(uint32_t u) { return __builtin_bit_cast(h2_t, u); }

__device__ __forceinline__ float sigf_(float x)  { return 1.0f / (1.0f + __expf(-x)); }
__device__ __forceinline__ float tanhf_(float x) { return 2.0f / (1.0f + __expf(-2.0f * x)) - 1.0f; }

__device__ __forceinline__ float laneb_(float v, int lane) {
  return __builtin_bit_cast(float, __builtin_amdgcn_readlane(__builtin_bit_cast(int, v), lane));
}
__device__ __forceinline__ uint32_t lanebu_(uint32_t v, int lane) {
  return (uint32_t)__builtin_amdgcn_readlane((int)v, lane);
}

// VALU lane-pair swap via DPP quad_perm[1,0,3,2] (0xB1): lane 2k <-> 2k+1.
// Replaces __shfl_xor(x,1) which lowers to ds_bpermute (~120 cyc LDS latency
// on the serial chain); DPP is ~2 cyc on the VALU pipe.
__device__ __forceinline__ float dppswap1_(float v) {
  return __builtin_bit_cast(float,
    __builtin_amdgcn_mov_dpp(__builtin_bit_cast(int, v), 0xB1, 0xF, 0xF, true));
}

// LDS-only barrier: waits LDS ops but does NOT drain vmem (HIP __syncthreads
// emits s_waitcnt vmcnt(0) which serializes prefetch/store pipelines).
__device__ __forceinline__ void barrier_lds_() {
  asm volatile("s_waitcnt lgkmcnt(0)" ::: "memory");
  __builtin_amdgcn_s_barrier();
}

// lstm lane->gate-rows mapping: wave w, lane L: unit = w*32 + (L>>1),
// role = L&1. role0 owns (i,g) rows, role1 owns (f,o). DPP(1) pairs them.
__device__ __forceinline__ void rows_of_(int tid, int& unit, int& role, int& r0, int& r1) {
  const int w = tid >> 6, L = tid & 63;
  unit = w * 32 + (L >> 1);
  role = L & 1;
  r0 = role * H_ + unit;            // i (role0) or f (role1)
  r1 = 2 * H_ + role * H_ + unit;   // g (role0) or o (role1)
}

// ---------------------------------------------------------------------------
// xw via MFMA 16x16x32 f16, PAIRED output layout:
//   xwp[dir][bt][ptid] = h2 { dot(x, Wih[r0(ptid)]), dot(x, Wih[r1(ptid)]) }
// so the lstm reads ONE coalesced dword per thread per step.
// Wave w covers gate block w (0=i,1=f,2=g,3=o): sel = w>>1, role = w&1.
// B-frags (Wih^T) register-resident; x staged in LDS f16 (K padded 80->96).
// ---------------------------------------------------------------------------
__global__ __launch_bounds__(256, 1)
void xw_kernel(const float* __restrict__ x,
               const float* __restrict__ Wih_f, const float* __restrict__ Wih_b,
               _Float16* __restrict__ xw)
{
  const int dir = blockIdx.x & 1;
  const int mc  = blockIdx.x >> 1;           // 0..99
  const float* W = dir ? Wih_b : Wih_f;

  const int tid  = threadIdx.x;
  const int w    = tid >> 6;
  const int lane = tid & 63;
  const int lm   = lane & 15;
  const int quad = lane >> 4;
  const int selw = w >> 1;                   // 0: i/f (.x slot), 1: g/o (.y slot)
  const int rolw = w & 1;

  f16x8 Bf[8][3];
  #pragma unroll
  for (int nt = 0; nt < 8; ++nt) {
    const int r = w * 128 + nt * 16 + lm;
    #pragma unroll
    for (int kt = 0; kt < 3; ++kt) {
      const int kb = kt * 32 + quad * 8;
      #pragma unroll
      for (int j = 0; j < 8; ++j) {
        const int k = kb + j;
        Bf[nt][kt][j] = (k < D_) ? (_Float16)W[(size_t)r * D_ + k] : (_Float16)0.0f;
      }
    }
  }

  __shared__ alignas(16) _Float16 xs[128 * 96];   // 24 KB, K padded to 96
  for (int i = tid; i < 128 * 96; i += 256) xs[i] = (_Float16)0.0f;

  for (int cc = 0; cc < 4; ++cc) {
    const int base = mc * 512 + cc * 128;
    __syncthreads();
    {
      const float4* src = (const float4*)(x + (size_t)base * D_);
      for (int i = tid; i < 128 * D_ / 4; i += 256) {
        float4 v = src[i];
        const int row = i / 20, col = (i % 20) * 4;
        h2_t p0, p1;
        p0.x = (_Float16)v.x; p0.y = (_Float16)v.y;
        p1.x = (_Float16)v.z; p1.y = (_Float16)v.w;
        uint2 pk;
        pk.x = __builtin_bit_cast(uint32_t, p0);
        pk.y = __builtin_bit_cast(uint32_t, p1);
        *(uint2*)&xs[row * 96 + col] = pk;
      }
    }
    __syncthreads();

    #pragma unroll
    for (int mt = 0; mt < 8; ++mt) {
      f16x8 Af[3];
      #pragma unroll
      for (int kt = 0; kt < 3; ++kt)
        Af[kt] = *(const f16x8*)&xs[(mt * 16 + lm) * 96 + kt * 32 + quad * 8];

      f32x4 acc[8];
      #pragma unroll
      for (int nt = 0; nt < 8; ++nt) acc[nt] = (f32x4){0.f, 0.f, 0.f, 0.f};
      #pragma unroll
      for (int kt = 0; kt < 3; ++kt)
        #pragma unroll
        for (int nt = 0; nt < 8; ++nt)
          acc[nt] = __builtin_amdgcn_mfma_f32_16x16x32_f16(Af[kt], Bf[nt][kt], acc[nt], 0, 0, 0);

      #pragma unroll
      for (int nt = 0; nt < 8; ++nt) {
        const int unit = nt * 16 + lm;
        const int ptid = (unit >> 5) * 64 + (unit & 31) * 2 + rolw;
        #pragma unroll
        for (int rg = 0; rg < 4; ++rg) {
          const int bt = base + mt * 16 + quad * 4 + rg;
          xw[((size_t)dir * BT_ + bt) * 512 + ptid * 2 + selw] = (_Float16)acc[nt][rg];
        }
      }
    }
  }
}

// ---------------------------------------------------------------------------
// Recurrent LSTM. Grid 128 (one WG per (b,dir)), 256 threads.
// h broadcast via readlane (1 ds_read_b32/wave/step), LDS-only barrier,
// double-buffered h by parity, DPP lane-pair gate exchange (no DS op on the
// chain). Paired xw: one coalesced dword load per thread per step,
// prefetched 2 steps ahead (never drained by the LDS-only barrier).
// ---------------------------------------------------------------------------
template<int USE_XW>
__global__ __launch_bounds__(256, 1)
void lstm_kernel(const float* __restrict__ x,
                 const float* __restrict__ Wih_f, const float* __restrict__ Whh_f,
                 const float* __restrict__ bih_f, const float* __restrict__ bhh_f,
                 const float* __restrict__ Wih_b, const float* __restrict__ Whh_b,
                 const float* __restrict__ bih_b, const float* __restrict__ bhh_b,
                 const _Float16* __restrict__ xw,
                 _Float16* __restrict__ hcat)
{
  const int bb  = blockIdx.x & 63;
  const int dir = blockIdx.x >> 6;
  const float* Whh = dir ? Whh_b : Whh_f;
  const float* Wih = dir ? Wih_b : Wih_f;
  const float* bih = dir ? bih_b : bih_f;
  const float* bhh = dir ? bhh_b : bhh_f;

  const int tid  = threadIdx.x;
  const int lane = tid & 63;
  int unit, role, r0, r1; rows_of_(tid, unit, role, r0, r1);

  h2_t w0[64], w1[64];
  #pragma unroll
  for (int j = 0; j < 64; ++j) {
    float2 a = *(const float2*)(Whh + (size_t)r0 * H_ + 2 * j);
    float2 d = *(const float2*)(Whh + (size_t)r1 * H_ + 2 * j);
    w0[j].x = (_Float16)a.x; w0[j].y = (_Float16)a.y;
    w1[j].x = (_Float16)d.x; w1[j].y = (_Float16)d.y;
  }
  h2_t wx0[40], wx1[40];
  if (!USE_XW) {
    #pragma unroll
    for (int i = 0; i < 40; ++i) {
      float2 a = *(const float2*)(Wih + (size_t)r0 * D_ + 2 * i);
      float2 d = *(const float2*)(Wih + (size_t)r1 * D_ + 2 * i);
      wx0[i].x = (_Float16)a.x; wx0[i].y = (_Float16)a.y;
      wx1[i].x = (_Float16)d.x; wx1[i].y = (_Float16)d.y;
    }
  }
  const float bias0 = bih[r0] + bhh[r0];
  const float bias1 = bih[r1] + bhh[r1];

  __shared__ alignas(8) _Float16 hsf[2][H_];   // double-buffered h
  __shared__ uint32_t xs2[2][64];              // fallback x staging

  if (tid < H_) hsf[0][tid] = (_Float16)0.0f;
  if (!USE_XW && tid < 64) { xs2[0][tid] = 0u; xs2[1][tid] = 0u; }
  float c = 0.0f;   // role1 owns cell state of its unit

  const uint32_t* xwdu = (const uint32_t*)xw + ((size_t)dir * BT_ + (size_t)bb * T_) * 256;
  const float*    xb   = x + (size_t)bb * T_ * D_;
  _Float16*       hb   = hcat + (size_t)bb * T_ * (2 * H_) + dir * H_;

  // prime the 2-deep prefetch pipeline
  uint32_t xwA = 0u, xwB = 0u;
  h2_t xpend; xpend.x = (_Float16)0.f; xpend.y = (_Float16)0.f;
  {
    const int tq0 = dir ? (T_ - 1) : 0;
    const int tq1 = dir ? (T_ - 2) : 1;
    if (USE_XW) {
      xwA = xwdu[(size_t)tq0 * 256 + tid];
      xwB = xwdu[(size_t)tq1 * 256 + tid];
    } else if (tid < 40) {
      float2 v0 = *(const float2*)(xb + (size_t)tq0 * D_ + 2 * tid);
      h2_t p; p.x = (_Float16)v0.x; p.y = (_Float16)v0.y;
      xs2[0][tid] = __builtin_bit_cast(uint32_t, p);
      float2 v1 = *(const float2*)(xb + (size_t)tq1 * D_ + 2 * tid);
      xpend.x = (_Float16)v1.x; xpend.y = (_Float16)v1.y;
    }
  }
  __syncthreads();

  auto step = [&](int tt, int par, uint32_t& xwreg) {
    const int t = dir ? (T_ - 1 - tt) : tt;
    float a0, a1, b0, b1;
    if (USE_XW) {
      const h2_t xv = asH2u_(xwreg);
      a0 = bias0 + (float)xv.x;
      b0 = bias1 + (float)xv.y;
      a1 = 0.f; b1 = 0.f;
      const int ttc = (tt + 2 < T_) ? (tt + 2) : (T_ - 1);
      const int tq2 = dir ? (T_ - 1 - ttc) : ttc;
      xwreg = xwdu[(size_t)tq2 * 256 + tid];   // prefetch; consumed 2 steps later
    } else {
      a0 = bias0; a1 = 0.f; b0 = bias1; b1 = 0.f;
      if (tid < 40) {
        xs2[par ^ 1][tid] = __builtin_bit_cast(uint32_t, xpend);
        const int ttc = (tt + 2 < T_) ? (tt + 2) : (T_ - 1);
        const int tq2 = dir ? (T_ - 1 - ttc) : ttc;
        float2 v = *(const float2*)(xb + (size_t)tq2 * D_ + 2 * tid);
        xpend.x = (_Float16)v.x; xpend.y = (_Float16)v.y;
      }
      uint32_t xreg = xs2[par][lane];
      #pragma unroll
      for (int j = 0; j < 40; j += 2) {
        h2_t q0 = asH2u_(lanebu_(xreg, j));
        h2_t q1 = asH2u_(lanebu_(xreg, j + 1));
        a0 = fdot2_(wx0[j],     q0, a0); b0 = fdot2_(wx1[j],     q0, b0);
        a1 = fdot2_(wx0[j + 1], q1, a1); b1 = fdot2_(wx1[j + 1], q1, b1);
      }
    }

    const uint32_t h2reg = ((const uint32_t*)hsf[par])[lane];
    #pragma unroll
    for (int j = 0; j < 64; j += 2) {
      h2_t hv0 = asH2u_(lanebu_(h2reg, j));
      h2_t hv1 = asH2u_(lanebu_(h2reg, j + 1));
      a0 = fdot2_(w0[j],     hv0, a0); b0 = fdot2_(w1[j],     hv0, b0);
      a1 = fdot2_(w0[j + 1], hv1, a1); b1 = fdot2_(w1[j + 1], hv1, b1);
    }
    const float ga = a0 + a1;   // i (role0) or f (role1)
    const float gb = b0 + b1;   // g (role0) or o (role1)

    float p = 0.f, sf = 0.f, so = 0.f;
    if (role == 0) p = sigf_(ga) * tanhf_(gb);
    else { sf = sigf_(ga); so = sigf_(gb); }
    const float ex = dppswap1_(p);              // VALU swap, lane 2k <-> 2k+1
    if (role) {
      c = sf * c + ex;
      const float h = so * tanhf_(c);
      hsf[par ^ 1][unit] = (_Float16)h;
      hb[(size_t)t * (2 * H_) + unit] = (_Float16)h;  // async, never drained
    }
    barrier_lds_();
  };

  for (int tb = 0; tb < T_; tb += 2) {
    step(tb,     0, xwA);
    step(tb + 1, 1, xwB);
  }
}

// ---------------------------------------------------------------------------
// Emissions via MFMA: em[bt][39] = hcat[bt][0:256] . Wp^T + bp.
// B-frags (Wp^T, N padded 39->48) register-resident; A-frags straight from
// global hcat. Grid 200, 4 m-tiles per wave.
// ---------------------------------------------------------------------------
__global__ __launch_bounds__(256, 1)
void emis_kernel(const _Float16* __restrict__ hcat,
                 const float* __restrict__ Wp, const float* __restrict__ bp,
                 float* __restrict__ em)
{
  const int tid  = threadIdx.x;
  const int w    = tid >> 6;
  const int lane = tid & 63;
  const int lm   = lane & 15;
  const int quad = lane >> 4;

  f16x8 Bf[3][8];
  float bias[3];
  #pragma unroll
  for (int nt = 0; nt < 3; ++nt) {
    const int n = nt * 16 + lm;
    const bool valid = n < K_;
    bias[nt] = valid ? bp[n] : 0.0f;
    #pragma unroll
    for (int kt = 0; kt < 8; ++kt) {
      const int kb = kt * 32 + quad * 8;
      #pragma unroll
      for (int j = 0; j < 8; ++j)
        Bf[nt][kt][j] = valid ? (_Float16)Wp[(size_t)n * 256 + kb + j] : (_Float16)0.0f;
    }
  }

  #pragma unroll
  for (int q = 0; q < 4; ++q) {
    const int mt  = blockIdx.x * 16 + w * 4 + q;
    const int bt0 = mt * 16;

    f16x8 Af[8];
    const _Float16* ab = hcat + ((size_t)bt0 + lm) * 256;
    #pragma unroll
    for (int kt = 0; kt < 8; ++kt)
      Af[kt] = *(const f16x8*)(ab + kt * 32 + quad * 8);

    f32x4 acc[3];
    #pragma unroll
    for (int nt = 0; nt < 3; ++nt) acc[nt] = (f32x4){0.f, 0.f, 0.f, 0.f};
    #pragma unroll
    for (int kt = 0; kt < 8; ++kt)
      #pragma unroll
      for (int nt = 0; nt < 3; ++nt)
        acc[nt] = __builtin_amdgcn_mfma_f32_16x16x32_f16(Af[kt], Bf[nt][kt], acc[nt], 0, 0, 0);

    #pragma unroll
    for (int nt = 0; nt < 3; ++nt) {
      const int n = nt * 16 + lm;
      if (n < K_) {
        #pragma unroll
        for (int rg = 0; rg < 4; ++rg) {
          const int row = bt0 + quad * 4 + rg;
          em[(size_t)row * K_ + n] = acc[nt][rg] + bias[nt];
        }
      }
    }
  }
}

// ---------------------------------------------------------------------------
// Numerator: masked reduction over t per batch element.
// ---------------------------------------------------------------------------
__global__ void crf_num_kernel(const int* __restrict__ labels, const int* __restrict__ lengths,
                               const float* __restrict__ em,
                               const float* __restrict__ start_t, const float* __restrict__ end_t,
                               const float* __restrict__ trans,
                               float* __restrict__ num)
{
  const int b = blockIdx.x;
  const int tid = threadIdx.x;   // 256
  const int len = lengths[b];
  float acc = 0.0f;
  for (int t = 1 + tid; t < len; t += 256) {
    int lp = labels[b * T_ + t - 1];
    int lc = labels[b * T_ + t];
    acc += trans[lp * K_ + lc] + em[((size_t)b * T_ + t) * K_ + lc];
  }
  __shared__ float red[256];
  red[tid] = acc;
  __syncthreads();
  for (int s = 128; s > 0; s >>= 1) {
    if (tid < s) red[tid] += red[tid + s];
    __syncthreads();
  }
  if (tid == 0) {
    int l0 = labels[b * T_];
    int ll = labels[b * T_ + len - 1];
    num[b] = red[0] + start_t[l0] + em[(size_t)b * T_ * K_ + l0] + end_t[ll];
  }
}

// ---------------------------------------------------------------------------
// Denominator: linear-space forward algorithm, one wave per batch element.
// All cross-lane DS ops removed from the loop: renormalize every 2 steps by
// lane 0's value (strictly positive; scale cancels exactly in the final log)
// via ONE readlane + rcp — the previous 6-deep shfl max chain was ~700 cyc
// of ds_bpermute latency on the serial critical path every 4 steps.
// ---------------------------------------------------------------------------
__global__ void crf_den_kernel(const float* __restrict__ em, const int* __restrict__ lengths,
                               const float* __restrict__ start_t, const float* __restrict__ end_t,
                               const float* __restrict__ trans,
                               float* __restrict__ den)
{
  const int b = blockIdx.x;
  const int k = threadIdx.x;     // 64 threads = 1 wave

  float et[K_];
  #pragma unroll
  for (int j = 0; j < K_; ++j)
    et[j] = (k < K_) ? __expf(trans[j * K_ + k]) : 0.0f;

  const int len = lengths[b];
  const float* emb = em + (size_t)b * T_ * K_;

  float a0 = (k < K_) ? (start_t[k] + emb[k]) : -1e30f;
  float m = a0;
  #pragma unroll
  for (int off = 32; off > 0; off >>= 1) m = fmaxf(m, __shfl_xor(m, off));
  float v = __expf(a0 - m);           // lanes >= 39 -> 0
  float off_acc = m;

  auto ld = [&](int t) -> float {
    int tc = (t < len) ? t : (len - 1);
    return (k < K_) ? emb[(size_t)tc * K_ + k] : 0.0f;
  };
  float e0 = ld(1), e1 = ld(2), e2 = ld(3), e3 = ld(4);

  for (int t = 1; t < len; ++t) {
    const float emc = e0;
    e0 = e1; e1 = e2; e2 = e3;
    e3 = ld(t + 4);

    const float pv = v;
    float s0 = 0.f, s1 = 0.f, s2 = 0.f, s3 = 0.f;
    #pragma unroll
    for (int j = 0; j < 36; j += 4) {
      s0 = fmaf(laneb_(pv, j),     et[j],     s0);
      s1 = fmaf(laneb_(pv, j + 1), et[j + 1], s1);
      s2 = fmaf(laneb_(pv, j + 2), et[j + 2], s2);
      s3 = fmaf(laneb_(pv, j + 3), et[j + 3], s3);
    }
    s0 = fmaf(laneb_(pv, 36), et[36], s0);
    s1 = fmaf(laneb_(pv, 37), et[37], s1);
    s2 = fmaf(laneb_(pv, 38), et[38], s2);

    v = ((s0 + s1) + (s2 + s3)) * __expf(emc);
    if ((t & 1) == 0) {               // cheap wave-uniform renorm, VALU only
      const float sc = laneb_(v, 0);  // > 0 always (all terms positive)
      v *= 1.0f / sc;
      off_acc += __logf(sc);
    }
  }

  float w = (k < K_) ? v * __expf(end_t[k]) : 0.0f;
  #pragma unroll
  for (int off = 32; off > 0; off >>= 1) w += __shfl_xor(w, off);
  if (k == 0) den[b] = off_acc + __logf(w);
}

__global__ void finalize_kernel(const float* __restrict__ num, const float* __restrict__ den,
                                float* __restrict__ out)
{
  const int tid = threadIdx.x;   // 64
  float v = den[tid] - num[tid];
  #pragma unroll
  for (int off = 32; off > 0; off >>= 1) v += __shfl_down(v, off);
  if (tid == 0) out[0] = v * (1.0f / 64.0f);
}

extern "C" void kernel_launch(void* const* d_in, const int* in_sizes, int n_in,
                              void* d_out, int out_size, void* d_ws, size_t ws_size,
                              hipStream_t stream)
{
  (void)in_sizes; (void)n_in; (void)out_size;
  const float* features = (const float*)d_in[0];
  const int*   lengths  = (const int*)d_in[1];
  const int*   labels   = (const int*)d_in[2];
  const float* Wih_f = (const float*)d_in[3];
  const float* Whh_f = (const float*)d_in[4];
  const float* bih_f = (const float*)d_in[5];
  const float* bhh_f = (const float*)d_in[6];
  const float* Wih_b = (const float*)d_in[7];
  const float* Whh_b = (const float*)d_in[8];
  const float* bih_b = (const float*)d_in[9];
  const float* bhh_b = (const float*)d_in[10];
  const float* Wp      = (const float*)d_in[11];
  const float* bp      = (const float*)d_in[12];
  const float* start_t = (const float*)d_in[13];
  const float* end_t   = (const float*)d_in[14];
  const float* trans   = (const float*)d_in[15];
  float* out = (float*)d_out;

  // ws layout (bytes): hcat f16 [0, 26214400) ; em f32 [26214400, +7987200) ;
  // num/den 512 B ; xw f16 [34202112, +104857600) if ws is big enough.
  char* wsc = (char*)d_ws;
  _Float16* hcatH = (_Float16*)wsc;
  float*    em    = (float*)(wsc + 26214400);
  float*    num   = (float*)(wsc + 26214400 + 7987200);
  float*    den   = num + B_;
  _Float16* xwH   = (_Float16*)(wsc + 34202112);
  const bool big  = ws_size >= (size_t)34202112 + 104857600;

  if (big) {
    hipLaunchKernelGGL(xw_kernel, dim3(200), dim3(256), 0, stream,
                       features, Wih_f, Wih_b, xwH);
    hipLaunchKernelGGL((lstm_kernel<1>), dim3(2 * B_), dim3(256), 0, stream,
                       features, Wih_f, Whh_f, bih_f, bhh_f,
                       Wih_b, Whh_b, bih_b, bhh_b, xwH, hcatH);
  } else {
    hipLaunchKernelGGL((lstm_kernel<0>), dim3(2 * B_), dim3(256), 0, stream,
                       features, Wih_f, Whh_f, bih_f, bhh_f,
                       Wih_b, Whh_b, bih_b, bhh_b, xwH, hcatH);
  }
  hipLaunchKernelGGL(emis_kernel, dim3(BT_ / 256), dim3(256), 0, stream,
                     hcatH, Wp, bp, em);
  hipLaunchKernelGGL(crf_num_kernel, dim3(B_), dim3(256), 0, stream,
                     labels, lengths, em, start_t, end_t, trans, num);
  hipLaunchKernelGGL(crf_den_kernel, dim3(B_), dim3(64), 0, stream,
                     em, lengths, start_t, end_t, trans, den);
  hipLaunchKernelGGL(finalize_kernel, dim3(1), dim3(64), 0, stream,
                     num, den, out);
}

// Round 10
// 865.684 us; speedup vs baseline: 1.2352x; 1.0119x over previous
//
#include <hip/hip_runtime.h>
#include <cstddef>
#include <cstdint>

#define B_ 64
#define T_ 800
#define D_ 80
#define H_ 128
#define K_ 39
#define BT_ (B_ * T_)   // 51200

typedef _Float16 h2_t  __attribute__((ext_vector_type(2)));
typedef _Float16 f16x8 __attribute__((ext_vector_type(8)));
typedef float    f32x4 __attribute__((ext_vector_type(4)));

__device__ __forceinline__ float fdot2_(h2_t a, h2_t b, float c) {
#if __has_builtin(__builtin_amdgcn_fdot2)
  return __builtin_amdgcn_fdot2(a, b, c, false);
#else
  return c + (float)a.x * (float)b.x + (float)a.y * (float)b.y;
#endif
}

__device__ __forceinline__ h2_t asH2u_(uint32_t u) { return __builtin_bit_cast(h2_t, u); }

__device__ __forceinline__ float sigf_(float x)  { return 1.0f / (1.0f + __expf(-x)); }
__device__ __forceinline__ float tanhf_(float x) { return 2.0f / (1.0f + __expf(-2.0f * x)) - 1.0f; }

__device__ __forceinline__ float laneb_(float v, int lane) {
  return __builtin_bit_cast(float, __builtin_amdgcn_readlane(__builtin_bit_cast(int, v), lane));
}
__device__ __forceinline__ uint32_t lanebu_(uint32_t v, int lane) {
  return (uint32_t)__builtin_amdgcn_readlane((int)v, lane);
}

// VALU lane-pair swap via DPP quad_perm[1,0,3,2] (0xB1): lane 2k <-> 2k+1.
__device__ __forceinline__ float dppswap1_(float v) {
  return __builtin_bit_cast(float,
    __builtin_amdgcn_mov_dpp(__builtin_bit_cast(int, v), 0xB1, 0xF, 0xF, true));
}

// LDS-only barrier: waits LDS ops but does NOT drain vmem.
__device__ __forceinline__ void barrier_lds_() {
  asm volatile("s_waitcnt lgkmcnt(0)" ::: "memory");
  __builtin_amdgcn_s_barrier();
}

// lstm lane->gate-rows mapping: wave w, lane L: unit = w*32 + (L>>1),
// role = L&1. role0 owns (i,g) rows, role1 owns (f,o). DPP(1) pairs them.
__device__ __forceinline__ void rows_of_(int tid, int& unit, int& role, int& r0, int& r1) {
  const int w = tid >> 6, L = tid & 63;
  unit = w * 32 + (L >> 1);
  role = L & 1;
  r0 = role * H_ + unit;            // i (role0) or f (role1)
  r1 = 2 * H_ + role * H_ + unit;   // g (role0) or o (role1)
}

// ---------------------------------------------------------------------------
// xw via MFMA 16x16x32 f16, PAIRED output layout (unchanged from R9).
// ---------------------------------------------------------------------------
__global__ __launch_bounds__(256, 1)
void xw_kernel(const float* __restrict__ x,
               const float* __restrict__ Wih_f, const float* __restrict__ Wih_b,
               _Float16* __restrict__ xw)
{
  const int dir = blockIdx.x & 1;
  const int mc  = blockIdx.x >> 1;           // 0..99
  const float* W = dir ? Wih_b : Wih_f;

  const int tid  = threadIdx.x;
  const int w    = tid >> 6;
  const int lane = tid & 63;
  const int lm   = lane & 15;
  const int quad = lane >> 4;
  const int selw = w >> 1;                   // 0: i/f (.x slot), 1: g/o (.y slot)
  const int rolw = w & 1;

  f16x8 Bf[8][3];
  #pragma unroll
  for (int nt = 0; nt < 8; ++nt) {
    const int r = w * 128 + nt * 16 + lm;
    #pragma unroll
    for (int kt = 0; kt < 3; ++kt) {
      const int kb = kt * 32 + quad * 8;
      #pragma unroll
      for (int j = 0; j < 8; ++j) {
        const int k = kb + j;
        Bf[nt][kt][j] = (k < D_) ? (_Float16)W[(size_t)r * D_ + k] : (_Float16)0.0f;
      }
    }
  }

  __shared__ alignas(16) _Float16 xs[128 * 96];   // 24 KB, K padded to 96
  for (int i = tid; i < 128 * 96; i += 256) xs[i] = (_Float16)0.0f;

  for (int cc = 0; cc < 4; ++cc) {
    const int base = mc * 512 + cc * 128;
    __syncthreads();
    {
      const float4* src = (const float4*)(x + (size_t)base * D_);
      for (int i = tid; i < 128 * D_ / 4; i += 256) {
        float4 v = src[i];
        const int row = i / 20, col = (i % 20) * 4;
        h2_t p0, p1;
        p0.x = (_Float16)v.x; p0.y = (_Float16)v.y;
        p1.x = (_Float16)v.z; p1.y = (_Float16)v.w;
        uint2 pk;
        pk.x = __builtin_bit_cast(uint32_t, p0);
        pk.y = __builtin_bit_cast(uint32_t, p1);
        *(uint2*)&xs[row * 96 + col] = pk;
      }
    }
    __syncthreads();

    #pragma unroll
    for (int mt = 0; mt < 8; ++mt) {
      f16x8 Af[3];
      #pragma unroll
      for (int kt = 0; kt < 3; ++kt)
        Af[kt] = *(const f16x8*)&xs[(mt * 16 + lm) * 96 + kt * 32 + quad * 8];

      f32x4 acc[8];
      #pragma unroll
      for (int nt = 0; nt < 8; ++nt) acc[nt] = (f32x4){0.f, 0.f, 0.f, 0.f};
      #pragma unroll
      for (int kt = 0; kt < 3; ++kt)
        #pragma unroll
        for (int nt = 0; nt < 8; ++nt)
          acc[nt] = __builtin_amdgcn_mfma_f32_16x16x32_f16(Af[kt], Bf[nt][kt], acc[nt], 0, 0, 0);

      #pragma unroll
      for (int nt = 0; nt < 8; ++nt) {
        const int unit = nt * 16 + lm;
        const int ptid = (unit >> 5) * 64 + (unit & 31) * 2 + rolw;
        #pragma unroll
        for (int rg = 0; rg < 4; ++rg) {
          const int bt = base + mt * 16 + quad * 4 + rg;
          xw[((size_t)dir * BT_ + bt) * 512 + ptid * 2 + selw] = (_Float16)acc[nt][rg];
        }
      }
    }
  }
}

// ---------------------------------------------------------------------------
// Recurrent LSTM (unchanged from R9).
// ---------------------------------------------------------------------------
template<int USE_XW>
__global__ __launch_bounds__(256, 1)
void lstm_kernel(const float* __restrict__ x,
                 const float* __restrict__ Wih_f, const float* __restrict__ Whh_f,
                 const float* __restrict__ bih_f, const float* __restrict__ bhh_f,
                 const float* __restrict__ Wih_b, const float* __restrict__ Whh_b,
                 const float* __restrict__ bih_b, const float* __restrict__ bhh_b,
                 const _Float16* __restrict__ xw,
                 _Float16* __restrict__ hcat)
{
  const int bb  = blockIdx.x & 63;
  const int dir = blockIdx.x >> 6;
  const float* Whh = dir ? Whh_b : Whh_f;
  const float* Wih = dir ? Wih_b : Wih_f;
  const float* bih = dir ? bih_b : bih_f;
  const float* bhh = dir ? bhh_b : bhh_f;

  const int tid  = threadIdx.x;
  const int lane = tid & 63;
  int unit, role, r0, r1; rows_of_(tid, unit, role, r0, r1);

  h2_t w0[64], w1[64];
  #pragma unroll
  for (int j = 0; j < 64; ++j) {
    float2 a = *(const float2*)(Whh + (size_t)r0 * H_ + 2 * j);
    float2 d = *(const float2*)(Whh + (size_t)r1 * H_ + 2 * j);
    w0[j].x = (_Float16)a.x; w0[j].y = (_Float16)a.y;
    w1[j].x = (_Float16)d.x; w1[j].y = (_Float16)d.y;
  }
  h2_t wx0[40], wx1[40];
  if (!USE_XW) {
    #pragma unroll
    for (int i = 0; i < 40; ++i) {
      float2 a = *(const float2*)(Wih + (size_t)r0 * D_ + 2 * i);
      float2 d = *(const float2*)(Wih + (size_t)r1 * D_ + 2 * i);
      wx0[i].x = (_Float16)a.x; wx0[i].y = (_Float16)a.y;
      wx1[i].x = (_Float16)d.x; wx1[i].y = (_Float16)d.y;
    }
  }
  const float bias0 = bih[r0] + bhh[r0];
  const float bias1 = bih[r1] + bhh[r1];

  __shared__ alignas(8) _Float16 hsf[2][H_];   // double-buffered h
  __shared__ uint32_t xs2[2][64];              // fallback x staging

  if (tid < H_) hsf[0][tid] = (_Float16)0.0f;
  if (!USE_XW && tid < 64) { xs2[0][tid] = 0u; xs2[1][tid] = 0u; }
  float c = 0.0f;   // role1 owns cell state of its unit

  const uint32_t* xwdu = (const uint32_t*)xw + ((size_t)dir * BT_ + (size_t)bb * T_) * 256;
  const float*    xb   = x + (size_t)bb * T_ * D_;
  _Float16*       hb   = hcat + (size_t)bb * T_ * (2 * H_) + dir * H_;

  uint32_t xwA = 0u, xwB = 0u;
  h2_t xpend; xpend.x = (_Float16)0.f; xpend.y = (_Float16)0.f;
  {
    const int tq0 = dir ? (T_ - 1) : 0;
    const int tq1 = dir ? (T_ - 2) : 1;
    if (USE_XW) {
      xwA = xwdu[(size_t)tq0 * 256 + tid];
      xwB = xwdu[(size_t)tq1 * 256 + tid];
    } else if (tid < 40) {
      float2 v0 = *(const float2*)(xb + (size_t)tq0 * D_ + 2 * tid);
      h2_t p; p.x = (_Float16)v0.x; p.y = (_Float16)v0.y;
      xs2[0][tid] = __builtin_bit_cast(uint32_t, p);
      float2 v1 = *(const float2*)(xb + (size_t)tq1 * D_ + 2 * tid);
      xpend.x = (_Float16)v1.x; xpend.y = (_Float16)v1.y;
    }
  }
  __syncthreads();

  auto step = [&](int tt, int par, uint32_t& xwreg) {
    const int t = dir ? (T_ - 1 - tt) : tt;
    float a0, a1, b0, b1;
    if (USE_XW) {
      const h2_t xv = asH2u_(xwreg);
      a0 = bias0 + (float)xv.x;
      b0 = bias1 + (float)xv.y;
      a1 = 0.f; b1 = 0.f;
      const int ttc = (tt + 2 < T_) ? (tt + 2) : (T_ - 1);
      const int tq2 = dir ? (T_ - 1 - ttc) : ttc;
      xwreg = xwdu[(size_t)tq2 * 256 + tid];   // prefetch; consumed 2 steps later
    } else {
      a0 = bias0; a1 = 0.f; b0 = bias1; b1 = 0.f;
      if (tid < 40) {
        xs2[par ^ 1][tid] = __builtin_bit_cast(uint32_t, xpend);
        const int ttc = (tt + 2 < T_) ? (tt + 2) : (T_ - 1);
        const int tq2 = dir ? (T_ - 1 - ttc) : ttc;
        float2 v = *(const float2*)(xb + (size_t)tq2 * D_ + 2 * tid);
        xpend.x = (_Float16)v.x; xpend.y = (_Float16)v.y;
      }
      uint32_t xreg = xs2[par][lane];
      #pragma unroll
      for (int j = 0; j < 40; j += 2) {
        h2_t q0 = asH2u_(lanebu_(xreg, j));
        h2_t q1 = asH2u_(lanebu_(xreg, j + 1));
        a0 = fdot2_(wx0[j],     q0, a0); b0 = fdot2_(wx1[j],     q0, b0);
        a1 = fdot2_(wx0[j + 1], q1, a1); b1 = fdot2_(wx1[j + 1], q1, b1);
      }
    }

    const uint32_t h2reg = ((const uint32_t*)hsf[par])[lane];
    #pragma unroll
    for (int j = 0; j < 64; j += 2) {
      h2_t hv0 = asH2u_(lanebu_(h2reg, j));
      h2_t hv1 = asH2u_(lanebu_(h2reg, j + 1));
      a0 = fdot2_(w0[j],     hv0, a0); b0 = fdot2_(w1[j],     hv0, b0);
      a1 = fdot2_(w0[j + 1], hv1, a1); b1 = fdot2_(w1[j + 1], hv1, b1);
    }
    const float ga = a0 + a1;   // i (role0) or f (role1)
    const float gb = b0 + b1;   // g (role0) or o (role1)

    float p = 0.f, sf = 0.f, so = 0.f;
    if (role == 0) p = sigf_(ga) * tanhf_(gb);
    else { sf = sigf_(ga); so = sigf_(gb); }
    const float ex = dppswap1_(p);              // VALU swap, lane 2k <-> 2k+1
    if (role) {
      c = sf * c + ex;
      const float h = so * tanhf_(c);
      hsf[par ^ 1][unit] = (_Float16)h;
      hb[(size_t)t * (2 * H_) + unit] = (_Float16)h;  // async, never drained
    }
    barrier_lds_();
  };

  for (int tb = 0; tb < T_; tb += 2) {
    step(tb,     0, xwA);
    step(tb + 1, 1, xwB);
  }
}

// ---------------------------------------------------------------------------
// Emissions via MFMA (unchanged from R9).
// ---------------------------------------------------------------------------
__global__ __launch_bounds__(256, 1)
void emis_kernel(const _Float16* __restrict__ hcat,
                 const float* __restrict__ Wp, const float* __restrict__ bp,
                 float* __restrict__ em)
{
  const int tid  = threadIdx.x;
  const int w    = tid >> 6;
  const int lane = tid & 63;
  const int lm   = lane & 15;
  const int quad = lane >> 4;

  f16x8 Bf[3][8];
  float bias[3];
  #pragma unroll
  for (int nt = 0; nt < 3; ++nt) {
    const int n = nt * 16 + lm;
    const bool valid = n < K_;
    bias[nt] = valid ? bp[n] : 0.0f;
    #pragma unroll
    for (int kt = 0; kt < 8; ++kt) {
      const int kb = kt * 32 + quad * 8;
      #pragma unroll
      for (int j = 0; j < 8; ++j)
        Bf[nt][kt][j] = valid ? (_Float16)Wp[(size_t)n * 256 + kb + j] : (_Float16)0.0f;
    }
  }

  #pragma unroll
  for (int q = 0; q < 4; ++q) {
    const int mt  = blockIdx.x * 16 + w * 4 + q;
    const int bt0 = mt * 16;

    f16x8 Af[8];
    const _Float16* ab = hcat + ((size_t)bt0 + lm) * 256;
    #pragma unroll
    for (int kt = 0; kt < 8; ++kt)
      Af[kt] = *(const f16x8*)(ab + kt * 32 + quad * 8);

    f32x4 acc[3];
    #pragma unroll
    for (int nt = 0; nt < 3; ++nt) acc[nt] = (f32x4){0.f, 0.f, 0.f, 0.f};
    #pragma unroll
    for (int kt = 0; kt < 8; ++kt)
      #pragma unroll
      for (int nt = 0; nt < 3; ++nt)
        acc[nt] = __builtin_amdgcn_mfma_f32_16x16x32_f16(Af[kt], Bf[nt][kt], acc[nt], 0, 0, 0);

    #pragma unroll
    for (int nt = 0; nt < 3; ++nt) {
      const int n = nt * 16 + lm;
      if (n < K_) {
        #pragma unroll
        for (int rg = 0; rg < 4; ++rg) {
          const int row = bt0 + quad * 4 + rg;
          em[(size_t)row * K_ + n] = acc[nt][rg] + bias[nt];
        }
      }
    }
  }
}

// ---------------------------------------------------------------------------
// Fused CRF denominator + numerator. Grid 64, 256 threads.
// Wave 0: serial linear-space forward algorithm with an 8-deep NAMED-register
//   em pipeline (no register rotation -> compiler emits vmcnt(7)-style waits
//   instead of the vmcnt(0)-per-step drain that made R9's "4-deep" pipeline
//   depth-1 and cost one full memory latency per step).
// Waves 1-3: parallel masked numerator reduction over t (192 threads).
// Combine at the end via LDS; dn[b] = den - num.
// ---------------------------------------------------------------------------
__global__ __launch_bounds__(256)
void crf_dn_kernel(const float* __restrict__ em,
                   const int* __restrict__ labels, const int* __restrict__ lengths,
                   const float* __restrict__ start_t, const float* __restrict__ end_t,
                   const float* __restrict__ trans,
                   float* __restrict__ dn)
{
  const int b    = blockIdx.x;
  const int tid  = threadIdx.x;
  const int wv   = tid >> 6;
  const int lane = tid & 63;
  const int len  = lengths[b];
  const float* emb = em + (size_t)b * T_ * K_;

  __shared__ float s_num[3];
  __shared__ float s_den;

  if (wv == 0) {
    // ---------------- serial denominator, 1 wave ----------------
    float et[K_];
    #pragma unroll
    for (int j = 0; j < K_; ++j)
      et[j] = (lane < K_) ? __expf(trans[j * K_ + lane]) : 0.0f;

    float a0 = (lane < K_) ? (start_t[lane] + emb[lane]) : -1e30f;
    float m = a0;
    #pragma unroll
    for (int off = 32; off > 0; off >>= 1) m = fmaxf(m, __shfl_xor(m, off));
    float v = __expf(a0 - m);           // lanes >= 39 -> 0
    float off_acc = m;

    auto ldc = [&](int t) -> float {
      const int tc = (t < len) ? t : (len - 1);
      return (lane < K_) ? emb[(size_t)tc * K_ + lane] : 0.0f;
    };

    // 8 NAMED pipeline registers — no rotation moves.
    float eA = ldc(1), eB = ldc(2), eC = ldc(3), eD = ldc(4);
    float eE = ldc(5), eF = ldc(6), eG = ldc(7), eH = ldc(8);

    auto stepden = [&](float& ereg, int tt) {
      const float emc = ereg;
      ereg = ldc(tt + 8);               // reload same named reg for tt+8
      if (tt < len) {                   // wave-uniform guard
        const float pv = v;
        float s0 = 0.f, s1 = 0.f, s2 = 0.f, s3 = 0.f;
        #pragma unroll
        for (int j = 0; j < 36; j += 4) {
          s0 = fmaf(laneb_(pv, j),     et[j],     s0);
          s1 = fmaf(laneb_(pv, j + 1), et[j + 1], s1);
          s2 = fmaf(laneb_(pv, j + 2), et[j + 2], s2);
          s3 = fmaf(laneb_(pv, j + 3), et[j + 3], s3);
        }
        s0 = fmaf(laneb_(pv, 36), et[36], s0);
        s1 = fmaf(laneb_(pv, 37), et[37], s1);
        s2 = fmaf(laneb_(pv, 38), et[38], s2);
        v = ((s0 + s1) + (s2 + s3)) * __expf(emc);
        if ((tt & 1) == 0) {            // VALU-only renorm (all terms > 0)
          const float sc = laneb_(v, 0);
          v *= 1.0f / sc;
          off_acc += __logf(sc);
        }
      }
    };

    for (int t = 1; t < len; t += 8) {
      stepden(eA, t);     stepden(eB, t + 1);
      stepden(eC, t + 2); stepden(eD, t + 3);
      stepden(eE, t + 4); stepden(eF, t + 5);
      stepden(eG, t + 6); stepden(eH, t + 7);
    }

    float w = (lane < K_) ? v * __expf(end_t[lane]) : 0.0f;
    #pragma unroll
    for (int off = 32; off > 0; off >>= 1) w += __shfl_xor(w, off);
    if (lane == 0) s_den = off_acc + __logf(w);
  } else {
    // ---------------- parallel numerator, 3 waves ----------------
    const int idx = tid - 64;           // 0..191
    float acc = 0.0f;
    for (int t = 1 + idx; t < len; t += 192) {
      const int lp = labels[b * T_ + t - 1];
      const int lc = labels[b * T_ + t];
      acc += trans[lp * K_ + lc] + emb[(size_t)t * K_ + lc];
    }
    if (tid == 64) {                    // edge terms on one lane
      const int l0 = labels[b * T_];
      const int ll = labels[b * T_ + len - 1];
      acc += start_t[l0] + emb[l0] + end_t[ll];
    }
    #pragma unroll
    for (int off = 32; off > 0; off >>= 1) acc += __shfl_xor(acc, off);
    if (lane == 0) s_num[wv - 1] = acc;
  }
  __syncthreads();
  if (tid == 0) dn[b] = s_den - (s_num[0] + s_num[1] + s_num[2]);
}

// out = mean(dn) over the 64 batch elements (one wave).
__global__ void finalize_kernel(const float* __restrict__ dn, float* __restrict__ out)
{
  const int tid = threadIdx.x;   // 64
  float v = dn[tid];
  #pragma unroll
  for (int off = 32; off > 0; off >>= 1) v += __shfl_down(v, off);
  if (tid == 0) out[0] = v * (1.0f / 64.0f);
}

extern "C" void kernel_launch(void* const* d_in, const int* in_sizes, int n_in,
                              void* d_out, int out_size, void* d_ws, size_t ws_size,
                              hipStream_t stream)
{
  (void)in_sizes; (void)n_in; (void)out_size;
  const float* features = (const float*)d_in[0];
  const int*   lengths  = (const int*)d_in[1];
  const int*   labels   = (const int*)d_in[2];
  const float* Wih_f = (const float*)d_in[3];
  const float* Whh_f = (const float*)d_in[4];
  const float* bih_f = (const float*)d_in[5];
  const float* bhh_f = (const float*)d_in[6];
  const float* Wih_b = (const float*)d_in[7];
  const float* Whh_b = (const float*)d_in[8];
  const float* bih_b = (const float*)d_in[9];
  const float* bhh_b = (const float*)d_in[10];
  const float* Wp      = (const float*)d_in[11];
  const float* bp      = (const float*)d_in[12];
  const float* start_t = (const float*)d_in[13];
  const float* end_t   = (const float*)d_in[14];
  const float* trans   = (const float*)d_in[15];
  float* out = (float*)d_out;

  // ws layout (bytes): hcat f16 [0, 26214400) ; em f32 [26214400, +7987200) ;
  // dn 256 B ; xw f16 [34202112, +104857600) if ws is big enough.
  char* wsc = (char*)d_ws;
  _Float16* hcatH = (_Float16*)wsc;
  float*    em    = (float*)(wsc + 26214400);
  float*    dn    = (float*)(wsc + 26214400 + 7987200);
  _Float16* xwH   = (_Float16*)(wsc + 34202112);
  const bool big  = ws_size >= (size_t)34202112 + 104857600;

  if (big) {
    hipLaunchKernelGGL(xw_kernel, dim3(200), dim3(256), 0, stream,
                       features, Wih_f, Wih_b, xwH);
    hipLaunchKernelGGL((lstm_kernel<1>), dim3(2 * B_), dim3(256), 0, stream,
                       features, Wih_f, Whh_f, bih_f, bhh_f,
                       Wih_b, Whh_b, bih_b, bhh_b, xwH, hcatH);
  } else {
    hipLaunchKernelGGL((lstm_kernel<0>), dim3(2 * B_), dim3(256), 0, stream,
                       features, Wih_f, Whh_f, bih_f, bhh_f,
                       Wih_b, Whh_b, bih_b, bhh_b, xwH, hcatH);
  }
  hipLaunchKernelGGL(emis_kernel, dim3(BT_ / 256), dim3(256), 0, stream,
                     hcatH, Wp, bp, em);
  hipLaunchKernelGGL(crf_dn_kernel, dim3(B_), dim3(256), 0, stream,
                     em, labels, lengths, start_t, end_t, trans, dn);
  hipLaunchKernelGGL(finalize_kernel, dim3(1), dim3(64), 0, stream,
                     dn, out);
}